// Round 7
// baseline (469.711 us; speedup 1.0000x reference)
//
#include <hip/hip_runtime.h>
#include <hip/hip_bf16.h>

#define D_MODEL 1536
#define NEXP    64
#define D_HID   512
#define NTOK    4096
#define NK1     (D_MODEL / 64)   // 24
#define NK2     (D_HID / 64)     // 8
#define MT      192              // packed M rows per block pass
#define LDSA    (MT * 64)        // 12288 elems
#define LDSB    (64 * 64)        // 4096 elems
#define BUF     (LDSA + LDSB)    // 16384 elems -> 32KB single buffer

typedef __attribute__((ext_vector_type(8))) short short8;
typedef __attribute__((ext_vector_type(4))) float f32x4;

__device__ __forceinline__ unsigned short f2bf(float f) {
  unsigned u = __builtin_bit_cast(unsigned, f);
  u += 0x7FFFu + ((u >> 16) & 1u);
  return (unsigned short)(u >> 16);
}

__device__ __forceinline__ unsigned pk2(float a, float b) {
  return (unsigned)f2bf(a) | ((unsigned)f2bf(b) << 16);
}

__device__ __forceinline__ float bf2f(unsigned short u) {
  return __builtin_bit_cast(float, ((unsigned)u) << 16);
}

// ---------------- utility ----------------

__global__ void zero_small_kernel(int* __restrict__ counts) {
  counts[threadIdx.x] = 0;
}

// ---------------- router (fp32, LDS-tiled, 8 tokens/block, fused x->bf16) ----------------

__global__ __launch_bounds__(256) void router_kernel(const float* __restrict__ x,
    const float* __restrict__ Wr, int* __restrict__ topidx, float* __restrict__ topw,
    int* __restrict__ counts, unsigned short* __restrict__ xb)
{
  __shared__ float xs[8][32];
  __shared__ float wst[32][64];
  const int tid  = threadIdx.x;
  const int lane = tid & 63;
  const int wv   = tid >> 6;
  const int t0   = blockIdx.x * 8;

  float acc[2][4];
  #pragma unroll
  for (int i = 0; i < 2; ++i)
    #pragma unroll
    for (int j = 0; j < 4; ++j) acc[i][j] = 0.f;

  for (int k0 = 0; k0 < D_MODEL; k0 += 32) {
    __syncthreads();
    {
      int r = tid >> 5, c = tid & 31;
      float xv = x[(long)(t0 + r) * D_MODEL + k0 + c];
      xs[r][c] = xv;
      xb[(long)(t0 + r) * D_MODEL + k0 + c] = f2bf(xv);   // fused conversion
    }
    {
      int e = tid >> 2, q = tid & 3;
      const float* wp = Wr + (long)e * D_MODEL + k0 + q * 8;
      float4 v0 = *(const float4*)wp;
      float4 v1 = *(const float4*)(wp + 4);
      int kk = q * 8;
      wst[kk + 0][e] = v0.x; wst[kk + 1][e] = v0.y; wst[kk + 2][e] = v0.z; wst[kk + 3][e] = v0.w;
      wst[kk + 4][e] = v1.x; wst[kk + 5][e] = v1.y; wst[kk + 6][e] = v1.z; wst[kk + 7][e] = v1.w;
    }
    __syncthreads();
    #pragma unroll
    for (int k = 0; k < 32; k += 4) {
      #pragma unroll
      for (int kb = 0; kb < 4; ++kb) {
        float wvv = wst[k + kb][lane];
        #pragma unroll
        for (int i = 0; i < 2; ++i)
          acc[i][kb] = fmaf(xs[wv * 2 + i][k + kb], wvv, acc[i][kb]);
      }
    }
  }
  float lg[2];
  #pragma unroll
  for (int i = 0; i < 2; ++i) lg[i] = (acc[i][0] + acc[i][1]) + (acc[i][2] + acc[i][3]);

  for (int i = 0; i < 2; ++i) {
    float v = lg[i];
    float v0 = v; int e0 = lane;
    #pragma unroll
    for (int off = 32; off > 0; off >>= 1) {
      float ov = __shfl_xor(v0, off);
      int   oe = __shfl_xor(e0, off);
      if (ov > v0 || (ov == v0 && oe < e0)) { v0 = ov; e0 = oe; }
    }
    float v1 = (lane == e0) ? -3.0e38f : v;
    int e1 = lane;
    #pragma unroll
    for (int off = 32; off > 0; off >>= 1) {
      float ov = __shfl_xor(v1, off);
      int   oe = __shfl_xor(e1, off);
      if (ov > v1 || (ov == v1 && oe < e1)) { v1 = ov; e1 = oe; }
    }
    if (lane == 0) {
      int t = t0 + wv * 2 + i;
      float w0 = 1.f / (1.f + expf(v1 - v0));
      topidx[t * 2]     = e0;
      topidx[t * 2 + 1] = e1;
      topw[t * 2]       = w0;
      topw[t * 2 + 1]   = 1.f - w0;
      atomicAdd(&counts[e0], 1);
      atomicAdd(&counts[e1], 1);
    }
  }
}

// ---------------- scan + scatter ----------------

__global__ void scan_kernel(const int* __restrict__ counts, int* __restrict__ offs,
                            int* __restrict__ cursor)
{
  int e = threadIdx.x;   // 64 threads
  int c = counts[e];
  int xx = c;
  #pragma unroll
  for (int off = 1; off < 64; off <<= 1) {
    int y = __shfl_up(xx, off);
    if (e >= off) xx += y;
  }
  offs[e + 1] = xx;
  if (e == 0) offs[0] = 0;
  cursor[e] = 0;
}

__global__ void scatter_kernel(const int* __restrict__ topidx, const float* __restrict__ topw,
    const int* __restrict__ offs, int* __restrict__ cursor,
    int* __restrict__ perm, float* __restrict__ wgt, int* __restrict__ tok2slot)
{
  int t = blockIdx.x * blockDim.x + threadIdx.x;
  if (t >= NTOK) return;
  #pragma unroll
  for (int k = 0; k < 2; ++k) {
    int e = topidx[t * 2 + k];
    float w = topw[t * 2 + k];
    int pos = atomicAdd(&cursor[e], 1);
    int slot = offs[e] + pos;
    perm[slot] = t;
    wgt[slot] = w;
    tok2slot[t * 2 + k] = slot;
  }
}

// ---------------- grouped FFN GEMMs (single 32KB LDS buffer, 4 blocks/CU) ----------------

__global__ __launch_bounds__(256, 4) void ffn1_kernel(
    const unsigned short* __restrict__ xb, const float* __restrict__ W1,
    const int* __restrict__ offs, const int* __restrict__ perm,
    const float* __restrict__ wgt, unsigned short* __restrict__ hbuf)
{
  const int e  = blockIdx.x;
  const int nc = blockIdx.y;                  // 0..7 : 64-col chunk of D_HID
  const int cnt = offs[e + 1] - offs[e];
  if (cnt == 0) return;

  __shared__ unsigned short lds[BUF];

  const int tid = threadIdx.x;
  const int lane = tid & 63;
  const int wv = tid >> 6;

  const int sA = tid & 7;
  const int rA = tid >> 3;
  const int qB = tid & 15;
  const int rB = tid >> 4;
  const float* bptr[4];
  #pragma unroll
  for (int p = 0; p < 4; ++p)
    bptr[p] = W1 + ((long)e * D_HID + nc * 64 + p * 16 + rB) * D_MODEL + qB * 4;

  int arow[3], brow[4];
  int physA[2][3], physB[2][4];
  #pragma unroll
  for (int mi = 0; mi < 3; ++mi) {
    arow[mi] = wv * 48 + mi * 16 + (lane & 15);
    #pragma unroll
    for (int ks = 0; ks < 2; ++ks)
      physA[ks][mi] = (ks * 4 + (lane >> 4)) ^ (arow[mi] & 7);
  }
  #pragma unroll
  for (int ni = 0; ni < 4; ++ni) {
    brow[ni] = ni * 16 + (lane & 15);
    #pragma unroll
    for (int ks = 0; ks < 2; ++ks)
      physB[ks][ni] = (ks * 4 + (lane >> 4)) ^ (brow[ni] & 7);
  }

  for (int m0 = 0; m0 < cnt; m0 += MT) {
    const int base = offs[e] + m0;
    const int mcnt = min(MT, cnt - m0);

    const unsigned short* aptr[6];
    #pragma unroll
    for (int p = 0; p < 6; ++p) {
      int pr = p * 32 + rA;
      aptr[p] = (pr < mcnt) ? xb + (long)perm[base + pr] * D_MODEL + sA * 8 : nullptr;
    }

    f32x4 acc[3][4];
    #pragma unroll
    for (int i = 0; i < 3; ++i)
      #pragma unroll
      for (int j = 0; j < 4; ++j) acc[i][j] = (f32x4)0.f;

    uint4 ar[6]; float4 br[4];

    auto LOAD = [&](int k0) {
      #pragma unroll
      for (int p = 0; p < 6; ++p)
        ar[p] = aptr[p] ? *(const uint4*)(aptr[p] + k0) : make_uint4(0u, 0u, 0u, 0u);
      #pragma unroll
      for (int p = 0; p < 4; ++p)
        br[p] = *(const float4*)(bptr[p] + k0);
    };
    auto WRITE = [&]() {
      unsigned short* A_ = lds;
      unsigned short* B_ = lds + LDSA;
      #pragma unroll
      for (int p = 0; p < 6; ++p) {
        int pr = p * 32 + rA;
        *(uint4*)(A_ + pr * 64 + (sA ^ (pr & 7)) * 8) = ar[p];
      }
      #pragma unroll
      for (int p = 0; p < 4; ++p) {
        int rr = p * 16 + rB;
        unsigned lo = pk2(br[p].x, br[p].y);
        unsigned hi = pk2(br[p].z, br[p].w);
        int ph = (qB >> 1) ^ (rr & 7);
        *(uint2*)(B_ + rr * 64 + ph * 8 + (qB & 1) * 4) = make_uint2(lo, hi);
      }
    };
    auto COMPUTE = [&]() {
      const unsigned short* A_ = lds;
      const unsigned short* B_ = lds + LDSA;
      #pragma unroll
      for (int ks = 0; ks < 2; ++ks) {
        short8 a[3], bb[4];
        #pragma unroll
        for (int mi = 0; mi < 3; ++mi)
          a[mi] = *(const short8*)(A_ + arow[mi] * 64 + physA[ks][mi] * 8);
        #pragma unroll
        for (int ni = 0; ni < 4; ++ni)
          bb[ni] = *(const short8*)(B_ + brow[ni] * 64 + physB[ks][ni] * 8);
        #pragma unroll
        for (int mi = 0; mi < 3; ++mi)
          #pragma unroll
          for (int ni = 0; ni < 4; ++ni)
            acc[mi][ni] = __builtin_amdgcn_mfma_f32_16x16x32_bf16(a[mi], bb[ni], acc[mi][ni], 0, 0, 0);
      }
    };

    LOAD(0);
    WRITE();
    __syncthreads();
    #pragma unroll 1
    for (int t = 0; t < NK1; ++t) {
      if (t + 1 < NK1) LOAD((t + 1) * 64);   // issue early: latency hides under COMPUTE
      COMPUTE();
      __syncthreads();                        // all waves done reading buffer
      if (t + 1 < NK1) {
        WRITE();                              // drain + restage
        __syncthreads();
      }
    }

    // epilogue: SiLU * gate -> bf16 hbuf
    const int rsub = (lane >> 4) * 4;
    const int csub = lane & 15;
    #pragma unroll
    for (int mi = 0; mi < 3; ++mi) {
      #pragma unroll
      for (int rg = 0; rg < 4; ++rg) {
        int r = wv * 48 + mi * 16 + rsub + rg;
        if (r < mcnt) {
          float wt = wgt[base + r];
          unsigned short* hrow = hbuf + (long)(base + r) * D_HID + nc * 64 + csub;
          #pragma unroll
          for (int ni = 0; ni < 4; ++ni) {
            float v = acc[mi][ni][rg];
            float sv = v / (1.f + __expf(-v)) * wt;
            hrow[ni * 16] = f2bf(sv);
          }
        }
      }
    }
    __syncthreads();
  }
}

__global__ __launch_bounds__(256, 4) void ffn2_kernel(
    const unsigned short* __restrict__ hbuf, const float* __restrict__ W2,
    const int* __restrict__ offs, unsigned short* __restrict__ sbuf)
{
  const int e  = blockIdx.x;
  const int nc = blockIdx.y;                  // 0..23 : 64-col chunk of D_MODEL
  const int cnt = offs[e + 1] - offs[e];
  if (cnt == 0) return;

  __shared__ unsigned short lds[BUF];

  const int tid = threadIdx.x;
  const int lane = tid & 63;
  const int wv = tid >> 6;

  const int sA = tid & 7;
  const int rA = tid >> 3;
  const int qB = tid & 15;
  const int rB = tid >> 4;
  const float* bptr[4];
  #pragma unroll
  for (int p = 0; p < 4; ++p)
    bptr[p] = W2 + ((long)e * D_MODEL + nc * 64 + p * 16 + rB) * D_HID + qB * 4;

  int arow[3], brow[4];
  int physA[2][3], physB[2][4];
  #pragma unroll
  for (int mi = 0; mi < 3; ++mi) {
    arow[mi] = wv * 48 + mi * 16 + (lane & 15);
    #pragma unroll
    for (int ks = 0; ks < 2; ++ks)
      physA[ks][mi] = (ks * 4 + (lane >> 4)) ^ (arow[mi] & 7);
  }
  #pragma unroll
  for (int ni = 0; ni < 4; ++ni) {
    brow[ni] = ni * 16 + (lane & 15);
    #pragma unroll
    for (int ks = 0; ks < 2; ++ks)
      physB[ks][ni] = (ks * 4 + (lane >> 4)) ^ (brow[ni] & 7);
  }

  for (int m0 = 0; m0 < cnt; m0 += MT) {
    const int base = offs[e] + m0;
    const int mcnt = min(MT, cnt - m0);

    const unsigned short* aptr[6];
    #pragma unroll
    for (int p = 0; p < 6; ++p) {
      int pr = p * 32 + rA;
      aptr[p] = (pr < mcnt) ? hbuf + (long)(base + pr) * D_HID + sA * 8 : nullptr;
    }

    f32x4 acc[3][4];
    #pragma unroll
    for (int i = 0; i < 3; ++i)
      #pragma unroll
      for (int j = 0; j < 4; ++j) acc[i][j] = (f32x4)0.f;

    uint4 ar[6]; float4 br[4];

    auto LOAD = [&](int k0) {
      #pragma unroll
      for (int p = 0; p < 6; ++p)
        ar[p] = aptr[p] ? *(const uint4*)(aptr[p] + k0) : make_uint4(0u, 0u, 0u, 0u);
      #pragma unroll
      for (int p = 0; p < 4; ++p)
        br[p] = *(const float4*)(bptr[p] + k0);
    };
    auto WRITE = [&]() {
      unsigned short* A_ = lds;
      unsigned short* B_ = lds + LDSA;
      #pragma unroll
      for (int p = 0; p < 6; ++p) {
        int pr = p * 32 + rA;
        *(uint4*)(A_ + pr * 64 + (sA ^ (pr & 7)) * 8) = ar[p];
      }
      #pragma unroll
      for (int p = 0; p < 4; ++p) {
        int rr = p * 16 + rB;
        unsigned lo = pk2(br[p].x, br[p].y);
        unsigned hi = pk2(br[p].z, br[p].w);
        int ph = (qB >> 1) ^ (rr & 7);
        *(uint2*)(B_ + rr * 64 + ph * 8 + (qB & 1) * 4) = make_uint2(lo, hi);
      }
    };
    auto COMPUTE = [&]() {
      const unsigned short* A_ = lds;
      const unsigned short* B_ = lds + LDSA;
      #pragma unroll
      for (int ks = 0; ks < 2; ++ks) {
        short8 a[3], bb[4];
        #pragma unroll
        for (int mi = 0; mi < 3; ++mi)
          a[mi] = *(const short8*)(A_ + arow[mi] * 64 + physA[ks][mi] * 8);
        #pragma unroll
        for (int ni = 0; ni < 4; ++ni)
          bb[ni] = *(const short8*)(B_ + brow[ni] * 64 + physB[ks][ni] * 8);
        #pragma unroll
        for (int mi = 0; mi < 3; ++mi)
          #pragma unroll
          for (int ni = 0; ni < 4; ++ni)
            acc[mi][ni] = __builtin_amdgcn_mfma_f32_16x16x32_bf16(a[mi], bb[ni], acc[mi][ni], 0, 0, 0);
      }
    };

    LOAD(0);
    WRITE();
    __syncthreads();
    #pragma unroll 1
    for (int t = 0; t < NK2; ++t) {
      if (t + 1 < NK2) LOAD((t + 1) * 64);
      COMPUTE();
      __syncthreads();
      if (t + 1 < NK2) {
        WRITE();
        __syncthreads();
      }
    }

    // epilogue: bf16 transpose via LDS -> coalesced uint4 stores into slot buffer
    unsigned short* fds = lds;                 // 192 x 64 ushort = 24KB (A region)
    const int rsub = (lane >> 4) * 4;
    const int csub = lane & 15;
    #pragma unroll
    for (int mi = 0; mi < 3; ++mi) {
      #pragma unroll
      for (int rg = 0; rg < 4; ++rg) {
        int r = wv * 48 + mi * 16 + rsub + rg;
        #pragma unroll
        for (int ni = 0; ni < 4; ++ni)
          fds[r * 64 + ni * 16 + csub] = f2bf(acc[mi][ni][rg]);
      }
    }
    __syncthreads();
    #pragma unroll
    for (int q = 0; q < 6; ++q) {
      int idx = q * 256 + tid;
      int row = idx >> 3, c8 = idx & 7;
      if (row < mcnt)
        *(uint4*)(sbuf + (long)(base + row) * D_MODEL + nc * 64 + c8 * 8) =
            *(const uint4*)(fds + row * 64 + c8 * 8);
    }
    __syncthreads();   // protect LDS before next pass
  }
}

// ---------------- gather + LayerNorm (bf16 sbuf) ----------------

__global__ __launch_bounds__(192) void ln_kernel(const unsigned short* __restrict__ sbuf,
    const int* __restrict__ tok2slot, float* __restrict__ out,
    const float* __restrict__ gamma, const float* __restrict__ beta)
{
  const int tid = threadIdx.x;
  const int t = blockIdx.x;
  const long r0 = (long)tok2slot[t * 2]     * D_MODEL;
  const long r1 = (long)tok2slot[t * 2 + 1] * D_MODEL;

  uint4 u0 = *(const uint4*)(sbuf + r0 + tid * 8);
  uint4 u1 = *(const uint4*)(sbuf + r1 + tid * 8);
  float v[8];
  {
    const unsigned* p0 = &u0.x;
    const unsigned* p1 = &u1.x;
    #pragma unroll
    for (int i = 0; i < 4; ++i) {
      v[i * 2]     = bf2f((unsigned short)(p0[i] & 0xFFFFu))  + bf2f((unsigned short)(p1[i] & 0xFFFFu));
      v[i * 2 + 1] = bf2f((unsigned short)(p0[i] >> 16))      + bf2f((unsigned short)(p1[i] >> 16));
    }
  }

  float s = 0.f, sq = 0.f;
  #pragma unroll
  for (int i = 0; i < 8; ++i) { s += v[i]; sq += v[i] * v[i]; }
  #pragma unroll
  for (int off = 32; off > 0; off >>= 1) {
    s  += __shfl_xor(s, off);
    sq += __shfl_xor(sq, off);
  }
  __shared__ float ss[3], sqs[3];
  int wv = tid >> 6;
  if ((tid & 63) == 0) { ss[wv] = s; sqs[wv] = sq; }
  __syncthreads();
  s  = ss[0] + ss[1] + ss[2];
  sq = sqs[0] + sqs[1] + sqs[2];
  const float inv = 1.f / (float)D_MODEL;
  float mu  = s * inv;
  float var = sq * inv - mu * mu;
  float rs  = 1.f / sqrtf(var + 1e-5f);

  float4 g1 = *(const float4*)(gamma + tid * 8);
  float4 g2 = *(const float4*)(gamma + tid * 8 + 4);
  float4 b1v = *(const float4*)(beta + tid * 8);
  float4 b2v = *(const float4*)(beta + tid * 8 + 4);
  float4 a, b;
  a.x = (v[0] - mu) * rs * g1.x + b1v.x;
  a.y = (v[1] - mu) * rs * g1.y + b1v.y;
  a.z = (v[2] - mu) * rs * g1.z + b1v.z;
  a.w = (v[3] - mu) * rs * g1.w + b1v.w;
  b.x = (v[4] - mu) * rs * g2.x + b2v.x;
  b.y = (v[5] - mu) * rs * g2.y + b2v.y;
  b.z = (v[6] - mu) * rs * g2.z + b2v.z;
  b.w = (v[7] - mu) * rs * g2.w + b2v.w;
  float* row = out + (long)t * D_MODEL;
  *(float4*)(row + tid * 8)     = a;
  *(float4*)(row + tid * 8 + 4) = b;
}

// ---------------- launch ----------------

extern "C" void kernel_launch(void* const* d_in, const int* in_sizes, int n_in,
                              void* d_out, int out_size, void* d_ws, size_t ws_size,
                              hipStream_t stream) {
  const float* x     = (const float*)d_in[0];
  const float* Wr    = (const float*)d_in[1];
  const float* W1    = (const float*)d_in[2];
  const float* W2    = (const float*)d_in[3];
  const float* gamma = (const float*)d_in[4];
  const float* beta  = (const float*)d_in[5];
  float* out = (float*)d_out;

  char* ws = (char*)d_ws;
  unsigned short* xb     = (unsigned short*)(ws + 0);          // 12,582,912
  unsigned short* hbuf   = (unsigned short*)(ws + 12582912);   //  8,388,608
  unsigned short* sbuf   = (unsigned short*)(ws + 20971520);   // 25,165,824
  int*   topidx   = (int*)  (ws + 46137344);                   // 32,768
  float* topw     = (float*)(ws + 46170112);                   // 32,768
  int*   counts   = (int*)  (ws + 46202880);                   // 256
  int*   cursor   = (int*)  (ws + 46203136);                   // 256
  int*   offs     = (int*)  (ws + 46203392);                   // 512
  int*   tok2slot = (int*)  (ws + 46203904);                   // 32,768
  int*   perm     = (int*)  (ws + 46236672);                   // 32,768
  float* wgt      = (float*)(ws + 46269440);                   // 32,768

  hipLaunchKernelGGL(zero_small_kernel, dim3(1), dim3(64), 0, stream, counts);
  hipLaunchKernelGGL(router_kernel, dim3(NTOK / 8), dim3(256), 0, stream, x, Wr, topidx, topw, counts, xb);
  hipLaunchKernelGGL(scan_kernel, dim3(1), dim3(64), 0, stream, counts, offs, cursor);
  hipLaunchKernelGGL(scatter_kernel, dim3(NTOK / 256), dim3(256), 0, stream, topidx, topw, offs, cursor, perm, wgt, tok2slot);
  hipLaunchKernelGGL(ffn1_kernel, dim3(NEXP, 8), dim3(256), 0, stream, xb, W1, offs, perm, wgt, hbuf);
  hipLaunchKernelGGL(ffn2_kernel, dim3(NEXP, 24), dim3(256), 0, stream, hbuf, W2, offs, sbuf);
  hipLaunchKernelGGL(ln_kernel, dim3(NTOK), dim3(192), 0, stream, sbuf, tok2slot, out, gamma, beta);
}

// Round 8
// 243.356 us; speedup vs baseline: 1.9301x; 1.9301x over previous
//
#include <hip/hip_runtime.h>
#include <hip/hip_bf16.h>

#define D_MODEL 1536
#define NEXP    64
#define D_HID   512
#define NTOK    4096
#define NT1     (D_MODEL / 64)   // 24 K-steps
#define NT2     (D_HID / 64)     // 8 K-steps
#define MT      192              // packed M rows per block pass

typedef __attribute__((ext_vector_type(8))) short short8;
typedef __attribute__((ext_vector_type(4))) float f32x4;

__device__ __forceinline__ unsigned short f2bf(float f) {
  unsigned u = __builtin_bit_cast(unsigned, f);
  u += 0x7FFFu + ((u >> 16) & 1u);
  return (unsigned short)(u >> 16);
}
__device__ __forceinline__ unsigned pk2(float a, float b) {
  return (unsigned)f2bf(a) | ((unsigned)f2bf(b) << 16);
}
__device__ __forceinline__ float bf2f(unsigned short u) {
  return __builtin_bit_cast(float, ((unsigned)u) << 16);
}

// global -> LDS direct (16B/lane, wave-uniform LDS base, per-lane global src)
__device__ __forceinline__ void gl16(const void* g, void* s) {
  __builtin_amdgcn_global_load_lds(
      (const __attribute__((address_space(1))) unsigned int*)g,
      (__attribute__((address_space(3))) unsigned int*)s, 16, 0, 0);
}

#define WAITV(N)  asm volatile("s_waitcnt vmcnt(" #N ")" ::: "memory")
#define WAITL0    asm volatile("s_waitcnt lgkmcnt(0)" ::: "memory")
#define SBAR      __builtin_amdgcn_s_barrier()
#define SCHED0    __builtin_amdgcn_sched_barrier(0)

// ---------------- utility ----------------

__global__ void zero_small_kernel(int* __restrict__ counts) {
  counts[threadIdx.x] = 0;
}

// ---------------- router (fp32, LDS-tiled, fused x->bf16) ----------------

__global__ __launch_bounds__(256) void router_kernel(const float* __restrict__ x,
    const float* __restrict__ Wr, int* __restrict__ topidx, float* __restrict__ topw,
    int* __restrict__ counts, unsigned short* __restrict__ xb)
{
  __shared__ float xs[8][32];
  __shared__ float wst[32][64];
  const int tid  = threadIdx.x;
  const int lane = tid & 63;
  const int wv   = tid >> 6;
  const int t0   = blockIdx.x * 8;

  float acc[2][4];
  #pragma unroll
  for (int i = 0; i < 2; ++i)
    #pragma unroll
    for (int j = 0; j < 4; ++j) acc[i][j] = 0.f;

  for (int k0 = 0; k0 < D_MODEL; k0 += 32) {
    __syncthreads();
    {
      int r = tid >> 5, c = tid & 31;
      float xv = x[(long)(t0 + r) * D_MODEL + k0 + c];
      xs[r][c] = xv;
      xb[(long)(t0 + r) * D_MODEL + k0 + c] = f2bf(xv);
    }
    {
      int e = tid >> 2, q = tid & 3;
      const float* wp = Wr + (long)e * D_MODEL + k0 + q * 8;
      float4 v0 = *(const float4*)wp;
      float4 v1 = *(const float4*)(wp + 4);
      int kk = q * 8;
      wst[kk + 0][e] = v0.x; wst[kk + 1][e] = v0.y; wst[kk + 2][e] = v0.z; wst[kk + 3][e] = v0.w;
      wst[kk + 4][e] = v1.x; wst[kk + 5][e] = v1.y; wst[kk + 6][e] = v1.z; wst[kk + 7][e] = v1.w;
    }
    __syncthreads();
    #pragma unroll
    for (int k = 0; k < 32; k += 4) {
      #pragma unroll
      for (int kb = 0; kb < 4; ++kb) {
        float wvv = wst[k + kb][lane];
        #pragma unroll
        for (int i = 0; i < 2; ++i)
          acc[i][kb] = fmaf(xs[wv * 2 + i][k + kb], wvv, acc[i][kb]);
      }
    }
  }
  float lg[2];
  #pragma unroll
  for (int i = 0; i < 2; ++i) lg[i] = (acc[i][0] + acc[i][1]) + (acc[i][2] + acc[i][3]);

  for (int i = 0; i < 2; ++i) {
    float v = lg[i];
    float v0 = v; int e0 = lane;
    #pragma unroll
    for (int off = 32; off > 0; off >>= 1) {
      float ov = __shfl_xor(v0, off);
      int   oe = __shfl_xor(e0, off);
      if (ov > v0 || (ov == v0 && oe < e0)) { v0 = ov; e0 = oe; }
    }
    float v1 = (lane == e0) ? -3.0e38f : v;
    int e1 = lane;
    #pragma unroll
    for (int off = 32; off > 0; off >>= 1) {
      float ov = __shfl_xor(v1, off);
      int   oe = __shfl_xor(e1, off);
      if (ov > v1 || (ov == v1 && oe < e1)) { v1 = ov; e1 = oe; }
    }
    if (lane == 0) {
      int t = t0 + wv * 2 + i;
      float w0 = 1.f / (1.f + expf(v1 - v0));
      topidx[t * 2]     = e0;
      topidx[t * 2 + 1] = e1;
      topw[t * 2]       = w0;
      topw[t * 2 + 1]   = 1.f - w0;
      atomicAdd(&counts[e0], 1);
      atomicAdd(&counts[e1], 1);
    }
  }
}

// ---------------- scan + scatter ----------------

__global__ void scan_kernel(const int* __restrict__ counts, int* __restrict__ offs,
                            int* __restrict__ cursor)
{
  int e = threadIdx.x;
  int c = counts[e];
  int xx = c;
  #pragma unroll
  for (int off = 1; off < 64; off <<= 1) {
    int y = __shfl_up(xx, off);
    if (e >= off) xx += y;
  }
  offs[e + 1] = xx;
  if (e == 0) offs[0] = 0;
  cursor[e] = 0;
}

__global__ void scatter_kernel(const int* __restrict__ topidx, const float* __restrict__ topw,
    const int* __restrict__ offs, int* __restrict__ cursor,
    int* __restrict__ perm, float* __restrict__ wgt, int* __restrict__ tok2slot)
{
  int t = blockIdx.x * blockDim.x + threadIdx.x;
  if (t >= NTOK) return;
  #pragma unroll
  for (int k = 0; k < 2; ++k) {
    int e = topidx[t * 2 + k];
    float w = topw[t * 2 + k];
    int pos = atomicAdd(&cursor[e], 1);
    int slot = offs[e] + pos;
    perm[slot] = t;
    wgt[slot] = w;
    tok2slot[t * 2 + k] = slot;
  }
}

// ---------------- ffn1: counted-vmcnt pipeline, A via global_load_lds ----------------
// grid (64 experts, 8 chunks of 64 cols); LDS: A dbuf 48K + B dbuf 16K = 64K -> 2 blocks/CU

__global__ __launch_bounds__(256, 2) void ffn1_kernel(
    const unsigned short* __restrict__ xb, const float* __restrict__ W1,
    const int* __restrict__ offs, const int* __restrict__ perm,
    const float* __restrict__ wgt, unsigned short* __restrict__ hbuf)
{
  const int e  = blockIdx.x;
  const int nc = blockIdx.y;
  const int cnt = offs[e + 1] - offs[e];
  if (cnt == 0) return;

  __shared__ unsigned short Abuf[2][MT * 64];
  __shared__ unsigned short Bbuf[2][64 * 64];

  const int tid  = threadIdx.x;
  const int lane = tid & 63;
  const int wv   = tid >> 6;

  // B staging roles (fp32 W1 -> regs -> cvt -> ds_write)
  const int qB = tid & 15;
  const int rB = tid >> 4;
  const float* bptr[4];
  #pragma unroll
  for (int p = 0; p < 4; ++p)
    bptr[p] = W1 + ((long)e * D_HID + nc * 64 + p * 16 + rB) * D_MODEL + qB * 4;

  // fragment read addressing (logical slot s lives at phys s^(r&7), 16B slots)
  int arow[3], brow[4];
  int physA[2][3], physB[2][4];
  #pragma unroll
  for (int mi = 0; mi < 3; ++mi) {
    arow[mi] = wv * 48 + mi * 16 + (lane & 15);
    #pragma unroll
    for (int ks = 0; ks < 2; ++ks)
      physA[ks][mi] = (ks * 4 + (lane >> 4)) ^ (arow[mi] & 7);
  }
  #pragma unroll
  for (int ni = 0; ni < 4; ++ni) {
    brow[ni] = ni * 16 + (lane & 15);
    #pragma unroll
    for (int ks = 0; ks < 2; ++ks)
      physB[ks][ni] = (ks * 4 + (lane >> 4)) ^ (brow[ni] & 7);
  }
  // A gload source: lane covers phys slot lane&7 of row q*8+(lane>>3);
  // logical slot there = (lane&7)^(lane>>3)  (row&7 == lane>>3)
  const int lslot = (lane & 7) ^ (lane >> 3);

  for (int m0 = 0; m0 < cnt; m0 += MT) {
    const int base = offs[e] + m0;
    const int mcnt = min(MT, cnt - m0);

    const unsigned short* gptrA[6];
    #pragma unroll
    for (int j = 0; j < 6; ++j) {
      int pr = (wv * 6 + j) * 8 + (lane >> 3);
      if (pr >= mcnt) pr = mcnt - 1;
      gptrA[j] = xb + (long)perm[base + pr] * D_MODEL + lslot * 8;
    }

    f32x4 acc[3][4];
    #pragma unroll
    for (int i = 0; i < 3; ++i)
      #pragma unroll
      for (int j = 0; j < 4; ++j) acc[i][j] = (f32x4)0.f;

    float4 bregA[4], bregB[4];

    auto ISSUE = [&](int t, float4* br, unsigned short* Ab) {
      const int k0 = t * 64;
      SCHED0;
      #pragma unroll
      for (int p = 0; p < 4; ++p) br[p] = *(const float4*)(bptr[p] + k0);
      SCHED0;
      #pragma unroll
      for (int j = 0; j < 6; ++j)
        gl16(gptrA[j] + k0, Ab + (wv * 6 + j) * 512);
      SCHED0;
    };
    auto WRITE_B = [&](const float4* br, unsigned short* B_) {
      #pragma unroll
      for (int p = 0; p < 4; ++p) {
        int rr = p * 16 + rB;
        unsigned lo = pk2(br[p].x, br[p].y);
        unsigned hi = pk2(br[p].z, br[p].w);
        int ph = (qB >> 1) ^ (rr & 7);
        *(uint2*)(B_ + rr * 64 + ph * 8 + (qB & 1) * 4) = make_uint2(lo, hi);
      }
    };
    auto COMPUTE = [&](const unsigned short* A_, const unsigned short* B_) {
      #pragma unroll
      for (int ks = 0; ks < 2; ++ks) {
        short8 a[3], bb[4];
        #pragma unroll
        for (int mi = 0; mi < 3; ++mi)
          a[mi] = *(const short8*)(A_ + arow[mi] * 64 + physA[ks][mi] * 8);
        #pragma unroll
        for (int ni = 0; ni < 4; ++ni)
          bb[ni] = *(const short8*)(B_ + brow[ni] * 64 + physB[ks][ni] * 8);
        #pragma unroll
        for (int mi = 0; mi < 3; ++mi)
          #pragma unroll
          for (int ni = 0; ni < 4; ++ni)
            acc[mi][ni] = __builtin_amdgcn_mfma_f32_16x16x32_bf16(a[mi], bb[ni], acc[mi][ni], 0, 0, 0);
      }
    };

    // prologue: tiles 0,1 in flight
    ISSUE(0, bregA, Abuf[0]);
    WAITV(6);                       // B(0) landed (A(0) gloads may linger)
    WRITE_B(bregA, Bbuf[0]);
    ISSUE(1, bregB, Abuf[1]);
    WAITV(10);                      // A(0) landed (tile 1's 10 remain)
    WAITL0;
    SBAR;

    #pragma unroll 1
    for (int t = 0; t < NT1; t += 2) {
      COMPUTE(Abuf[0], Bbuf[0]);                 // tile t
      SBAR;                                      // readers done (Abuf0/Bbuf0, prev Bbuf1 free)
      WAITV(6);                                  // B(t+1) regs ready
      WRITE_B(bregB, Bbuf[1]);
      if (t + 2 < NT1) { ISSUE(t + 2, bregA, Abuf[0]); WAITV(10); }
      else             { WAITV(0); }
      WAITL0;
      SBAR;                                      // tile t+1 staged for all
      COMPUTE(Abuf[1], Bbuf[1]);                 // tile t+1
      SBAR;
      if (t + 2 < NT1) {
        WAITV(6);                                // B(t+2) regs ready
        WRITE_B(bregA, Bbuf[0]);
        if (t + 3 < NT1) { ISSUE(t + 3, bregB, Abuf[1]); WAITV(10); }
        else             { WAITV(0); }
        WAITL0;
        SBAR;
      }
    }

    // epilogue: SiLU * gate -> bf16 hbuf
    const int rsub = (lane >> 4) * 4;
    const int csub = lane & 15;
    #pragma unroll
    for (int mi = 0; mi < 3; ++mi) {
      #pragma unroll
      for (int rg = 0; rg < 4; ++rg) {
        int r = wv * 48 + mi * 16 + rsub + rg;
        if (r < mcnt) {
          float wt = wgt[base + r];
          unsigned short* hrow = hbuf + (long)(base + r) * D_HID + nc * 64 + csub;
          #pragma unroll
          for (int ni = 0; ni < 4; ++ni) {
            float v = acc[mi][ni][rg];
            float sv = v / (1.f + __expf(-v)) * wt;
            hrow[ni * 16] = f2bf(sv);
          }
        }
      }
    }
    __syncthreads();   // full drain before next m-pass reuses LDS
  }
}

// ---------------- ffn2: same pipeline, A = hbuf (contiguous slots) ----------------

__global__ __launch_bounds__(256, 2) void ffn2_kernel(
    const unsigned short* __restrict__ hbuf, const float* __restrict__ W2,
    const int* __restrict__ offs, unsigned short* __restrict__ sbuf)
{
  const int e  = blockIdx.x;
  const int nc = blockIdx.y;
  const int cnt = offs[e + 1] - offs[e];
  if (cnt == 0) return;

  __shared__ unsigned short Abuf[2][MT * 64];
  __shared__ unsigned short Bbuf[2][64 * 64];

  const int tid  = threadIdx.x;
  const int lane = tid & 63;
  const int wv   = tid >> 6;

  const int qB = tid & 15;
  const int rB = tid >> 4;
  const float* bptr[4];
  #pragma unroll
  for (int p = 0; p < 4; ++p)
    bptr[p] = W2 + ((long)e * D_MODEL + nc * 64 + p * 16 + rB) * D_HID + qB * 4;

  int arow[3], brow[4];
  int physA[2][3], physB[2][4];
  #pragma unroll
  for (int mi = 0; mi < 3; ++mi) {
    arow[mi] = wv * 48 + mi * 16 + (lane & 15);
    #pragma unroll
    for (int ks = 0; ks < 2; ++ks)
      physA[ks][mi] = (ks * 4 + (lane >> 4)) ^ (arow[mi] & 7);
  }
  #pragma unroll
  for (int ni = 0; ni < 4; ++ni) {
    brow[ni] = ni * 16 + (lane & 15);
    #pragma unroll
    for (int ks = 0; ks < 2; ++ks)
      physB[ks][ni] = (ks * 4 + (lane >> 4)) ^ (brow[ni] & 7);
  }
  const int lslot = (lane & 7) ^ (lane >> 3);

  for (int m0 = 0; m0 < cnt; m0 += MT) {
    const int base = offs[e] + m0;
    const int mcnt = min(MT, cnt - m0);

    const unsigned short* gptrA[6];
    #pragma unroll
    for (int j = 0; j < 6; ++j) {
      int pr = (wv * 6 + j) * 8 + (lane >> 3);
      if (pr >= mcnt) pr = mcnt - 1;
      gptrA[j] = hbuf + (long)(base + pr) * D_HID + lslot * 8;
    }

    f32x4 acc[3][4];
    #pragma unroll
    for (int i = 0; i < 3; ++i)
      #pragma unroll
      for (int j = 0; j < 4; ++j) acc[i][j] = (f32x4)0.f;

    float4 bregA[4], bregB[4];

    auto ISSUE = [&](int t, float4* br, unsigned short* Ab) {
      const int k0 = t * 64;
      SCHED0;
      #pragma unroll
      for (int p = 0; p < 4; ++p) br[p] = *(const float4*)(bptr[p] + k0);
      SCHED0;
      #pragma unroll
      for (int j = 0; j < 6; ++j)
        gl16(gptrA[j] + k0, Ab + (wv * 6 + j) * 512);
      SCHED0;
    };
    auto WRITE_B = [&](const float4* br, unsigned short* B_) {
      #pragma unroll
      for (int p = 0; p < 4; ++p) {
        int rr = p * 16 + rB;
        unsigned lo = pk2(br[p].x, br[p].y);
        unsigned hi = pk2(br[p].z, br[p].w);
        int ph = (qB >> 1) ^ (rr & 7);
        *(uint2*)(B_ + rr * 64 + ph * 8 + (qB & 1) * 4) = make_uint2(lo, hi);
      }
    };
    auto COMPUTE = [&](const unsigned short* A_, const unsigned short* B_) {
      #pragma unroll
      for (int ks = 0; ks < 2; ++ks) {
        short8 a[3], bb[4];
        #pragma unroll
        for (int mi = 0; mi < 3; ++mi)
          a[mi] = *(const short8*)(A_ + arow[mi] * 64 + physA[ks][mi] * 8);
        #pragma unroll
        for (int ni = 0; ni < 4; ++ni)
          bb[ni] = *(const short8*)(B_ + brow[ni] * 64 + physB[ks][ni] * 8);
        #pragma unroll
        for (int mi = 0; mi < 3; ++mi)
          #pragma unroll
          for (int ni = 0; ni < 4; ++ni)
            acc[mi][ni] = __builtin_amdgcn_mfma_f32_16x16x32_bf16(a[mi], bb[ni], acc[mi][ni], 0, 0, 0);
      }
    };

    ISSUE(0, bregA, Abuf[0]);
    WAITV(6);
    WRITE_B(bregA, Bbuf[0]);
    ISSUE(1, bregB, Abuf[1]);
    WAITV(10);
    WAITL0;
    SBAR;

    #pragma unroll 1
    for (int t = 0; t < NT2; t += 2) {
      COMPUTE(Abuf[0], Bbuf[0]);
      SBAR;
      WAITV(6);
      WRITE_B(bregB, Bbuf[1]);
      if (t + 2 < NT2) { ISSUE(t + 2, bregA, Abuf[0]); WAITV(10); }
      else             { WAITV(0); }
      WAITL0;
      SBAR;
      COMPUTE(Abuf[1], Bbuf[1]);
      SBAR;
      if (t + 2 < NT2) {
        WAITV(6);
        WRITE_B(bregA, Bbuf[0]);
        if (t + 3 < NT2) { ISSUE(t + 3, bregB, Abuf[1]); WAITV(10); }
        else             { WAITV(0); }
        WAITL0;
        SBAR;
      }
    }

    // epilogue: bf16 transpose via LDS (Abuf[0] as scratch) -> coalesced uint4 stores
    unsigned short* fds = &Abuf[0][0];
    const int rsub = (lane >> 4) * 4;
    const int csub = lane & 15;
    #pragma unroll
    for (int mi = 0; mi < 3; ++mi) {
      #pragma unroll
      for (int rg = 0; rg < 4; ++rg) {
        int r = wv * 48 + mi * 16 + rsub + rg;
        #pragma unroll
        for (int ni = 0; ni < 4; ++ni)
          fds[r * 64 + ni * 16 + csub] = f2bf(acc[mi][ni][rg]);
      }
    }
    __syncthreads();
    #pragma unroll
    for (int q = 0; q < 6; ++q) {
      int idx = q * 256 + tid;
      int row = idx >> 3, c8 = idx & 7;
      if (row < mcnt)
        *(uint4*)(sbuf + (long)(base + row) * D_MODEL + nc * 64 + c8 * 8) =
            *(const uint4*)(fds + row * 64 + c8 * 8);
    }
    __syncthreads();
  }
}

// ---------------- gather + LayerNorm (bf16 sbuf) ----------------

__global__ __launch_bounds__(192) void ln_kernel(const unsigned short* __restrict__ sbuf,
    const int* __restrict__ tok2slot, float* __restrict__ out,
    const float* __restrict__ gamma, const float* __restrict__ beta)
{
  const int tid = threadIdx.x;
  const int t = blockIdx.x;
  const long r0 = (long)tok2slot[t * 2]     * D_MODEL;
  const long r1 = (long)tok2slot[t * 2 + 1] * D_MODEL;

  uint4 u0 = *(const uint4*)(sbuf + r0 + tid * 8);
  uint4 u1 = *(const uint4*)(sbuf + r1 + tid * 8);
  float v[8];
  {
    const unsigned* p0 = &u0.x;
    const unsigned* p1 = &u1.x;
    #pragma unroll
    for (int i = 0; i < 4; ++i) {
      v[i * 2]     = bf2f((unsigned short)(p0[i] & 0xFFFFu)) + bf2f((unsigned short)(p1[i] & 0xFFFFu));
      v[i * 2 + 1] = bf2f((unsigned short)(p0[i] >> 16))     + bf2f((unsigned short)(p1[i] >> 16));
    }
  }

  float s = 0.f, sq = 0.f;
  #pragma unroll
  for (int i = 0; i < 8; ++i) { s += v[i]; sq += v[i] * v[i]; }
  #pragma unroll
  for (int off = 32; off > 0; off >>= 1) {
    s  += __shfl_xor(s, off);
    sq += __shfl_xor(sq, off);
  }
  __shared__ float ss[3], sqs[3];
  int wv = tid >> 6;
  if ((tid & 63) == 0) { ss[wv] = s; sqs[wv] = sq; }
  __syncthreads();
  s  = ss[0] + ss[1] + ss[2];
  sq = sqs[0] + sqs[1] + sqs[2];
  const float inv = 1.f / (float)D_MODEL;
  float mu  = s * inv;
  float var = sq * inv - mu * mu;
  float rs  = 1.f / sqrtf(var + 1e-5f);

  float4 g1 = *(const float4*)(gamma + tid * 8);
  float4 g2 = *(const float4*)(gamma + tid * 8 + 4);
  float4 b1v = *(const float4*)(beta + tid * 8);
  float4 b2v = *(const float4*)(beta + tid * 8 + 4);
  float4 a, b;
  a.x = (v[0] - mu) * rs * g1.x + b1v.x;
  a.y = (v[1] - mu) * rs * g1.y + b1v.y;
  a.z = (v[2] - mu) * rs * g1.z + b1v.z;
  a.w = (v[3] - mu) * rs * g1.w + b1v.w;
  b.x = (v[4] - mu) * rs * g2.x + b2v.x;
  b.y = (v[5] - mu) * rs * g2.y + b2v.y;
  b.z = (v[6] - mu) * rs * g2.z + b2v.z;
  b.w = (v[7] - mu) * rs * g2.w + b2v.w;
  float* row = out + (long)t * D_MODEL;
  *(float4*)(row + tid * 8)     = a;
  *(float4*)(row + tid * 8 + 4) = b;
}

// ---------------- launch ----------------

extern "C" void kernel_launch(void* const* d_in, const int* in_sizes, int n_in,
                              void* d_out, int out_size, void* d_ws, size_t ws_size,
                              hipStream_t stream) {
  const float* x     = (const float*)d_in[0];
  const float* Wr    = (const float*)d_in[1];
  const float* W1    = (const float*)d_in[2];
  const float* W2    = (const float*)d_in[3];
  const float* gamma = (const float*)d_in[4];
  const float* beta  = (const float*)d_in[5];
  float* out = (float*)d_out;

  char* ws = (char*)d_ws;
  unsigned short* xb     = (unsigned short*)(ws + 0);          // 12,582,912
  unsigned short* hbuf   = (unsigned short*)(ws + 12582912);   //  8,388,608
  unsigned short* sbuf   = (unsigned short*)(ws + 20971520);   // 25,165,824
  int*   topidx   = (int*)  (ws + 46137344);
  float* topw     = (float*)(ws + 46170112);
  int*   counts   = (int*)  (ws + 46202880);
  int*   cursor   = (int*)  (ws + 46203136);
  int*   offs     = (int*)  (ws + 46203392);
  int*   tok2slot = (int*)  (ws + 46203904);
  int*   perm     = (int*)  (ws + 46236672);
  float* wgt      = (float*)(ws + 46269440);

  hipLaunchKernelGGL(zero_small_kernel, dim3(1), dim3(64), 0, stream, counts);
  hipLaunchKernelGGL(router_kernel, dim3(NTOK / 8), dim3(256), 0, stream, x, Wr, topidx, topw, counts, xb);
  hipLaunchKernelGGL(scan_kernel, dim3(1), dim3(64), 0, stream, counts, offs, cursor);
  hipLaunchKernelGGL(scatter_kernel, dim3(NTOK / 256), dim3(256), 0, stream, topidx, topw, offs, cursor, perm, wgt, tok2slot);
  hipLaunchKernelGGL(ffn1_kernel, dim3(NEXP, 8), dim3(256), 0, stream, xb, W1, offs, perm, wgt, hbuf);
  hipLaunchKernelGGL(ffn2_kernel, dim3(NEXP, 24), dim3(256), 0, stream, hbuf, W2, offs, sbuf);
  hipLaunchKernelGGL(ln_kernel, dim3(NTOK), dim3(192), 0, stream, sbuf, tok2slot, out, gamma, beta);
}